// Round 18
// baseline (139.604 us; speedup 1.0000x reference)
//
#include <hip/hip_runtime.h>
#include <stdint.h>

// ---------------------------------------------------------------------------
// GPT-2 attention block on gfx950.  B=4, S=2048, D=1024, H=16, HD=64.
//   1. prep:      z<4: W_z fp32 [K][N] -> bf16 [N][K];  z=4: X fp32 -> bf16
//   2. gemmS<0>:  QKV = X@[Wq|Wk|Wv]+b  (m97 structure, 128x128, BK=64)
//   3. attn:      flash causal attention, 512 thr = 8 waves x 32 q-rows,
//                 jq-PAIRED blocks: each block runs q-tiles {7-p, p}
//                 sequentially -> every block = 36 staged tiles, grid 256
//                 = exactly 1 block/CU, zero imbalance tail.
//   4. gemmS<1>:  out = attn@Wo + bo, fp32
// ---------------------------------------------------------------------------

#define GAS __attribute__((address_space(1)))
#define LAS __attribute__((address_space(3)))

typedef __attribute__((ext_vector_type(4))) float f32x4;
typedef __attribute__((ext_vector_type(8))) short bf16x8;

__device__ __forceinline__ short f2bf(float f) {
  union { float f; uint32_t u; } v; v.f = f;
  uint32_t r = v.u + 0x7fffu + ((v.u >> 16) & 1u);  // RNE
  return (short)(r >> 16);
}

__device__ __forceinline__ float bf2f(short s) {
  union { uint32_t u; float f; } v;
  v.u = ((uint32_t)(uint16_t)s) << 16;
  return v.f;
}

__device__ __forceinline__ uint32_t cvt_pk_bf16(float lo, float hi) {
  uint32_t r;
  asm("v_cvt_pk_bf16_f32 %0, %1, %2" : "=v"(r) : "v"(lo), "v"(hi));
  return r;
}

__device__ __forceinline__ void gload_lds16(const void* g, void* l) {
  // 16B per lane; LDS dest = wave-uniform base + lane*16 (linear)
  __builtin_amdgcn_global_load_lds((const GAS void*)g, (LAS void*)l, 16, 0, 0);
}

// (GATE used only by attn)
#define GATE(N)                                            \
  __builtin_amdgcn_sched_barrier(0);                       \
  asm volatile("s_waitcnt vmcnt(" #N ")" ::: "memory");    \
  __builtin_amdgcn_s_barrier();                            \
  __builtin_amdgcn_sched_barrier(0);

// ---------------- prep: 4x W transpose + X convert, one launch -------------
__global__ __launch_bounds__(256) void prep_kernel(const float* __restrict__ X,
                                                   const float* __restrict__ W0,
                                                   const float* __restrict__ W1,
                                                   const float* __restrict__ W2,
                                                   const float* __restrict__ W3,
                                                   short* __restrict__ Xbf,
                                                   short* __restrict__ Wt) {
  const int z = blockIdx.z;
  const int t = threadIdx.x;
  if (z == 4) {
    const int bid = blockIdx.x * 16 + blockIdx.y;
    const float4* src = (const float4*)X;
    short4* dst = (short4*)Xbf;
#pragma unroll
    for (int i = 0; i < 32; ++i) {
      const int idx = bid * 8192 + i * 256 + t;
      float4 v = src[idx];
      short4 o;
      o.x = f2bf(v.x); o.y = f2bf(v.y); o.z = f2bf(v.z); o.w = f2bf(v.w);
      dst[idx] = o;
    }
    return;
  }
  __shared__ short tile[64][65];
  const float* W = (z == 0) ? W0 : (z == 1) ? W1 : (z == 2) ? W2 : W3;
  short* dst = Wt + ((size_t)z << 20);
  const int k0 = blockIdx.x * 64, n0 = blockIdx.y * 64;
#pragma unroll
  for (int i = 0; i < 16; ++i) {
    int r = (t >> 6) + i * 4, c = t & 63;
    tile[r][c] = f2bf(W[(size_t)(k0 + r) * 1024 + n0 + c]);
  }
  __syncthreads();
#pragma unroll
  for (int i = 0; i < 16; ++i) {
    int r = (t >> 6) + i * 4, c = t & 63;
    dst[(size_t)(n0 + r) * 1024 + k0 + c] = tile[c][r];
  }
}

// ---------------- m97-structure bf16 GEMM, 128x128, BK=64 ----------------
template <int MODE>
__global__ __launch_bounds__(256, 2) void gemmS(const short* __restrict__ A,
                                                const short* __restrict__ Bt,
                                                const float* __restrict__ b0,
                                                const float* __restrict__ b1,
                                                const float* __restrict__ b2,
                                                void* __restrict__ O0,
                                                void* __restrict__ O1,
                                                void* __restrict__ O2) {
  __shared__ short lds[2][16384];  // [buf][ A:0..8191 | B:8192..16383 ]
  const int xcd = (int)blockIdx.x & 7;
  const int t = (int)blockIdx.x >> 3;
  const int m0 = (xcd * 8 + (t & 7)) * 128;  // 8 m-tiles chunked per XCD
  const int n0 = (t >> 3) * 128;             // N advances within chunk
  const int tid = threadIdx.x;
  const int lane = tid & 63, w = tid >> 6;
  const int l15 = lane & 15, lg = lane >> 4;
  const int wm = w >> 1, wn = w & 1;

  const short* ag[4];
  const short* bg[4];
#pragma unroll
  for (int i = 0; i < 4; ++i) {
    const int P = i * 256 + w * 64 + lane;   // physical 16B chunk 0..1023
    const int row = P >> 3, cl = (P & 7) ^ (row & 7);
    ag[i] = A + (size_t)(m0 + row) * 1024 + cl * 8;
    bg[i] = Bt + (size_t)(n0 + row) * 1024 + cl * 8;
  }

  int aof[4], bof[4];
#pragma unroll
  for (int f = 0; f < 4; ++f) {
    const int ra = wm * 64 + f * 16 + l15;
    aof[f] = ra * 64 + ((lg ^ (ra & 7)) * 8);
    const int rb = wn * 64 + f * 16 + l15;
    bof[f] = 8192 + rb * 64 + ((lg ^ (rb & 7)) * 8);
  }

  f32x4 acc[4][4];
#pragma unroll
  for (int i = 0; i < 4; ++i)
#pragma unroll
    for (int j = 0; j < 4; ++j) acc[i][j] = (f32x4){0.f, 0.f, 0.f, 0.f};

  auto stage = [&](int bi, int kt) {
#pragma unroll
    for (int i = 0; i < 4; ++i) {
      gload_lds16(ag[i] + kt * 64, &lds[bi][(i * 256 + w * 64) * 8]);
      gload_lds16(bg[i] + kt * 64, &lds[bi][8192 + (i * 256 + w * 64) * 8]);
    }
  };

  auto compute = [&](int bi) {
    const short* sl = &lds[bi][0];
#pragma unroll
    for (int kk = 0; kk < 2; ++kk) {
      bf16x8 a[4], b[4];
#pragma unroll
      for (int mf = 0; mf < 4; ++mf) a[mf] = *(const bf16x8*)&sl[aof[mf] ^ (kk * 32)];
#pragma unroll
      for (int nf = 0; nf < 4; ++nf) b[nf] = *(const bf16x8*)&sl[bof[nf] ^ (kk * 32)];
#pragma unroll
      for (int mf = 0; mf < 4; ++mf)
#pragma unroll
        for (int nf = 0; nf < 4; ++nf)
          acc[mf][nf] =
              __builtin_amdgcn_mfma_f32_16x16x32_bf16(a[mf], b[nf], acc[mf][nf], 0, 0, 0);
    }
  };

  stage(0, 0);
  __syncthreads();
  int cur = 0;
  for (int kt = 0; kt < 16; ++kt) {
    if (kt + 1 < 16) stage(cur ^ 1, kt + 1);
    compute(cur);
    __syncthreads();
    cur ^= 1;
  }

  if (MODE == 1) {
    float* dst = (float*)O0;
#pragma unroll
    for (int mf = 0; mf < 4; ++mf)
#pragma unroll
      for (int nf = 0; nf < 4; ++nf) {
        const int col = n0 + wn * 64 + nf * 16 + l15;
        const float bv = b0[col];
#pragma unroll
        for (int rr = 0; rr < 4; ++rr) {
          const int row = m0 + wm * 64 + mf * 16 + lg * 4 + rr;
          dst[(size_t)row * 1024 + col] = acc[mf][nf][rr] + bv;
        }
      }
  } else {
    const int mat = n0 >> 10;  // 0=Q 1=K 2=V
    const int nc0 = n0 & 1023;
    const float* bias = (mat == 0) ? b0 : (mat == 1) ? b1 : b2;
    if (mat < 2) {
      short* dst = (short*)(mat == 0 ? O0 : O1);
#pragma unroll
      for (int mf = 0; mf < 4; ++mf)
#pragma unroll
        for (int nf = 0; nf < 4; ++nf) {
          const int col = nc0 + wn * 64 + nf * 16 + l15;
          const float bv = bias[col];
          const int h = col >> 6, hd = col & 63;
#pragma unroll
          for (int rr = 0; rr < 4; ++rr) {
            const int row = m0 + wm * 64 + mf * 16 + lg * 4 + rr;
            const int b = row >> 11, s = row & 2047;
            dst[((size_t)(b * 16 + h) * 2048 + s) * 64 + hd] = f2bf(acc[mf][nf][rr] + bv);
          }
        }
    } else {
      // V: transposed AND k-permuted into Vt [B*16+h][64][2048]:
      // within each 32-k group, stored pos = lg*8 + hi*4 + e for k = hi*16+lg*4+e
      short* dst = (short*)O2;
#pragma unroll
      for (int mf = 0; mf < 4; ++mf) {
        const int rowb = m0 + wm * 64 + mf * 16 + lg * 4;
        const int b = rowb >> 11, s = rowb & 2047;
        const int s2 = (s & ~31) | (((s >> 2) & 3) << 3) | (((s >> 4) & 1) << 2);
#pragma unroll
        for (int nf = 0; nf < 4; ++nf) {
          const int col = nc0 + wn * 64 + nf * 16 + l15;
          const float bv = bias[col];
          const int h = col >> 6, hd = col & 63;
          short4 sv;
          sv.x = f2bf(acc[mf][nf][0] + bv);
          sv.y = f2bf(acc[mf][nf][1] + bv);
          sv.z = f2bf(acc[mf][nf][2] + bv);
          sv.w = f2bf(acc[mf][nf][3] + bv);
          *(short4*)&dst[((size_t)(b * 16 + h) * 64 + hd) * 2048 + s2] = sv;
        }
      }
    }
  }
}

// ---------------- flash causal attention, 512 thr, jq-paired ----------------
// Q,K: [64bh][2048][64] bf16; Vt: [64bh][64][2048] bf16 (k-permuted);
// out: [B,S,1024] bf16.  8 waves x 32 q-rows per q-tile of 256 rows.
// Block g handles q-tiles {7-p, p} (p = g>>6) sequentially: total staged
// tiles = 4(7-p)+4 + 4p+4 = 36 for EVERY block; grid 256 = 1 block/CU.
// Unnormalized p = exp2(s); MFMA ones-column row sums; 3-buf ring GATE(2).
__global__ __launch_bounds__(512) void attn_kernel(const short* __restrict__ Q,
                                                   const short* __restrict__ K,
                                                   const short* __restrict__ Vt,
                                                   short* __restrict__ Oout) {
  __shared__ short Ks[3][4096];
  __shared__ short Vs[3][4096];
  const int g = (int)blockIdx.x;
  const int bh = (((g >> 3) & 7) << 3) | (g & 7);  // XCD-local bh
  const int p = g >> 6;                            // 0..3
  const int tid = threadIdx.x;
  const int lane = tid & 63, w = tid >> 6;  // w in 0..7
  const int l15 = lane & 15, lg = lane >> 4;
  const short* Qb = Q + (size_t)bh * 2048 * 64;
  const short* Kb = K + (size_t)bh * 2048 * 64;
  const short* Vb = Vt + (size_t)bh * 64 * 2048;
  const int b = bh >> 4, h = bh & 15;
  const float SC = 0.18033688011112042f;  // 0.125 * log2(e)

  // ones B-frag for row-sum MFMA
  union { short s[8]; bf16x8 v; } one_u;
#pragma unroll
  for (int i = 0; i < 8; ++i) one_u.s[i] = (short)0x3F80;

  // per-thread pre-swizzled staging sources (1 K-load + 1 V-load per thread)
  const int Lsw = tid ^ ((tid >> 3) & 7);
  const short* kg = Kb + (size_t)(Lsw >> 3) * 64 + (Lsw & 7) * 8;
  const short* vg = Vb + (size_t)(Lsw >> 3) * 2048 + (Lsw & 7) * 8;

  // swizzled LDS read offsets (both K and V are b128)
  int kcol[2];
#pragma unroll
  for (int kk = 0; kk < 2; ++kk)
    kcol[kk] = (((kk * 4 + lg) ^ (l15 & 7)) << 3);

  auto stageKV = [&](int bi, int kt) {
    gload_lds16(kg + (size_t)kt * 4096, &Ks[bi][w * 512]);
    gload_lds16(vg + kt * 64, &Vs[bi][w * 512]);
  };

#pragma unroll 1
  for (int half = 0; half < 2; ++half) {
    const int jq = half == 0 ? (7 - p) : p;  // heavy tile first
    const int q0 = jq * 256;
    const int qg0 = q0 + w * 32;  // wave's first q row

    // Q fragments in registers, pre-scaled by 0.125*log2e
    bf16x8 qf[2][2];
#pragma unroll
    for (int qs = 0; qs < 2; ++qs)
#pragma unroll
      for (int kk = 0; kk < 2; ++kk) {
        bf16x8 rq =
            *(const bf16x8*)&Qb[(size_t)(qg0 + qs * 16 + l15) * 64 + kk * 32 + lg * 8];
        union { uint32_t u[4]; bf16x8 v; } sq;
#pragma unroll
        for (int d = 0; d < 4; ++d)
          sq.u[d] = cvt_pk_bf16(bf2f(rq[2 * d]) * SC, bf2f(rq[2 * d + 1]) * SC);
        qf[qs][kk] = sq.v;
      }

    f32x4 o[2][4];
#pragma unroll
    for (int i = 0; i < 2; ++i)
#pragma unroll
      for (int j = 0; j < 4; ++j) o[i][j] = (f32x4){0.f, 0.f, 0.f, 0.f};
    f32x4 psacc[2] = {(f32x4){0.f, 0.f, 0.f, 0.f}, (f32x4){0.f, 0.f, 0.f, 0.f}};

    const int nkt = 4 * jq + 4;
    // prologue: 2 tiles in flight (2 loads/wave each)
    stageKV(0, 0);
    stageKV(1, 1);

    int cur = 0;
    for (int kt = 0; kt < nkt; ++kt) {
      if (kt + 1 < nkt) {
        GATE(2)   // tile kt's 2 ops retired; kt+1's stay in flight
      } else {
        GATE(0)
      }
      if (kt + 2 < nkt) {
        int nb = cur + 2; if (nb >= 3) nb -= 3;
        stageKV(nb, kt + 2);  // overwrites buffer read at kt-1 (published)
      }

      if (kt * 64 <= qg0 + 31) {  // wave-uniform skip of fully-masked tiles
        const short* Kc = &Ks[cur][0];
        const short* Vc = &Vs[cur][0];

        // S^T = K @ Q^T : k = kt*64 + t*16 + lg*4 + r, q col = l15 (+16*qs)
        f32x4 sacc[4][2];
#pragma unroll
        for (int t = 0; t < 4; ++t)
#pragma unroll
          for (int qs = 0; qs < 2; ++qs) sacc[t][qs] = (f32x4){0.f, 0.f, 0.f, 0.f};
        __builtin_amdgcn_s_setprio(1);
#pragma unroll
        for (int t = 0; t < 4; ++t) {
          const int krow = (t * 16 + l15) * 64;
#pragma unroll
          for (int kk = 0; kk < 2; ++kk) {
            bf16x8 kf = *(const bf16x8*)&Kc[krow + kcol[kk]];
#pragma unroll
            for (int qs = 0; qs < 2; ++qs)
              sacc[t][qs] = __builtin_amdgcn_mfma_f32_16x16x32_bf16(kf, qf[qs][kk],
                                                                    sacc[t][qs], 0, 0, 0);
          }
        }
        __builtin_amdgcn_s_setprio(0);

        // causal mask — only the wave's diagonal region (wave-uniform test)
        if (kt * 64 + 63 > qg0) {
#pragma unroll
          for (int t = 0; t < 4; ++t)
#pragma unroll
            for (int qs = 0; qs < 2; ++qs)
#pragma unroll
              for (int r = 0; r < 4; ++r) {
                const int kg_ = kt * 64 + t * 16 + lg * 4 + r;
                const int qg = qg0 + qs * 16 + l15;
                if (kg_ > qg) sacc[t][qs][r] = -3e38f;
              }
        }

        // fixed-shift softmax: p = exp2(s); pack to bf16 A-frags
        bf16x8 pa[2][2];
#pragma unroll
        for (int qs = 0; qs < 2; ++qs) {
#pragma unroll
          for (int t = 0; t < 4; ++t)
#pragma unroll
            for (int r = 0; r < 4; ++r)
              sacc[t][qs][r] = __builtin_amdgcn_exp2f(sacc[t][qs][r]);
#pragma unroll
          for (int kk = 0; kk < 2; ++kk) {
            union { uint32_t u[4]; bf16x8 v; } pw;
            pw.u[0] = cvt_pk_bf16(sacc[2 * kk][qs][0], sacc[2 * kk][qs][1]);
            pw.u[1] = cvt_pk_bf16(sacc[2 * kk][qs][2], sacc[2 * kk][qs][3]);
            pw.u[2] = cvt_pk_bf16(sacc[2 * kk + 1][qs][0], sacc[2 * kk + 1][qs][1]);
            pw.u[3] = cvt_pk_bf16(sacc[2 * kk + 1][qs][2], sacc[2 * kk + 1][qs][3]);
            pa[qs][kk] = pw.v;
          }
        }

        // PV + row-sum MFMAs (one setprio cluster)
        __builtin_amdgcn_s_setprio(1);
#pragma unroll
        for (int ds = 0; ds < 4; ++ds) {
          const int vrow = (ds * 16 + l15) * 64;
#pragma unroll
          for (int kk = 0; kk < 2; ++kk) {
            bf16x8 vf = *(const bf16x8*)&Vc[vrow + kcol[kk]];
#pragma unroll
            for (int qs = 0; qs < 2; ++qs)
              o[qs][ds] = __builtin_amdgcn_mfma_f32_16x16x32_bf16(pa[qs][kk], vf,
                                                                  o[qs][ds], 0, 0, 0);
          }
        }
#pragma unroll
        for (int qs = 0; qs < 2; ++qs)
#pragma unroll
          for (int kk = 0; kk < 2; ++kk)
            psacc[qs] = __builtin_amdgcn_mfma_f32_16x16x32_bf16(pa[qs][kk], one_u.v,
                                                                psacc[qs], 0, 0, 0);
        __builtin_amdgcn_s_setprio(0);
      }

      cur = cur + 1 == 3 ? 0 : cur + 1;
    }

    // normalize + write; psacc layout == o layout (row = lg*4+r) -> lane-local
#pragma unroll
    for (int qs = 0; qs < 2; ++qs) {
      float inv[4];
#pragma unroll
      for (int r = 0; r < 4; ++r) inv[r] = 1.f / psacc[qs][r];
#pragma unroll
      for (int ds = 0; ds < 4; ++ds)
#pragma unroll
        for (int r = 0; r < 4; ++r) {
          const int qg = qg0 + qs * 16 + lg * 4 + r;
          const int col = h * 64 + ds * 16 + l15;
          Oout[((size_t)(b * 2048 + qg)) * 1024 + col] = f2bf(o[qs][ds][r] * inv[r]);
        }
    }
    __syncthreads();  // all LDS reads done before next half restarts the ring
  }
}

// ---------------------------------------------------------------------------
extern "C" void kernel_launch(void* const* d_in, const int* in_sizes, int n_in,
                              void* d_out, int out_size, void* d_ws, size_t ws_size,
                              hipStream_t stream) {
  const float* hs = (const float*)d_in[0];
  const float* Wq = (const float*)d_in[1];
  const float* bq = (const float*)d_in[2];
  const float* Wk = (const float*)d_in[3];
  const float* bk = (const float*)d_in[4];
  const float* Wv = (const float*)d_in[5];
  const float* bv = (const float*)d_in[6];
  const float* Wo = (const float*)d_in[7];
  const float* bo = (const float*)d_in[8];

  char* ws = (char*)d_ws;
  short* Xbf = (short*)(ws + 0);                  // 16 MB, reused as attn out
  short* Qb  = (short*)(ws + ((size_t)16 << 20)); // 16 MB
  short* Kb  = (short*)(ws + ((size_t)32 << 20)); // 16 MB
  short* Vtb = (short*)(ws + ((size_t)48 << 20)); // 16 MB
  short* Wts = (short*)(ws + ((size_t)64 << 20)); // 8 MB: Wqt|Wkt|Wvt|Wot
  short* Wot = Wts + ((size_t)3 << 20);

  prep_kernel<<<dim3(16, 16, 5), 256, 0, stream>>>(hs, Wq, Wk, Wv, Wo, Xbf, Wts);

  // QKV: M=8192 (64 tiles), N=3072 (24 tiles) -> 1536 blocks (6/CU exact)
  gemmS<0><<<1536, 256, 0, stream>>>(Xbf, Wts, bq, bk, bv, Qb, Kb, Vtb);

  attn_kernel<<<256, 512, 0, stream>>>(Qb, Kb, Vtb, Xbf);

  // out-proj: M=8192 (64), N=1024 (8) -> 512 blocks
  gemmS<1><<<512, 256, 0, stream>>>(Xbf, Wot, bo, nullptr, nullptr,
                                    (float*)d_out, nullptr, nullptr);
}

// Round 19
// 135.441 us; speedup vs baseline: 1.0307x; 1.0307x over previous
//
#include <hip/hip_runtime.h>
#include <stdint.h>

// ---------------------------------------------------------------------------
// GPT-2 attention block on gfx950.  B=4, S=2048, D=1024, H=16, HD=64.
//   1. prep:      z<4: W_z fp32 [K][N] -> bf16 [N][K];  z=4: X fp32 -> bf16
//   2. gemmS<0>:  QKV = X@[Wq|Wk|Wv]+b  (m97 structure, 128x128, BK=64,
//                 2-buf 64KB, plain __syncthreads — best of 9 variants)
//   3. attn:      flash causal attention, 512 thr = 8 waves x 32 q-rows
//                 (QBLK=256, shared K/V staging), fixed-shift softmax,
//                 3-buf ring, GATE(2).  [round-17 measured-best config]
//   4. gemmS<1>:  out = attn@Wo + bo, fp32
// ---------------------------------------------------------------------------

#define GAS __attribute__((address_space(1)))
#define LAS __attribute__((address_space(3)))

typedef __attribute__((ext_vector_type(4))) float f32x4;
typedef __attribute__((ext_vector_type(8))) short bf16x8;

__device__ __forceinline__ short f2bf(float f) {
  union { float f; uint32_t u; } v; v.f = f;
  uint32_t r = v.u + 0x7fffu + ((v.u >> 16) & 1u);  // RNE
  return (short)(r >> 16);
}

__device__ __forceinline__ float bf2f(short s) {
  union { uint32_t u; float f; } v;
  v.u = ((uint32_t)(uint16_t)s) << 16;
  return v.f;
}

__device__ __forceinline__ uint32_t cvt_pk_bf16(float lo, float hi) {
  uint32_t r;
  asm("v_cvt_pk_bf16_f32 %0, %1, %2" : "=v"(r) : "v"(lo), "v"(hi));
  return r;
}

__device__ __forceinline__ void gload_lds16(const void* g, void* l) {
  // 16B per lane; LDS dest = wave-uniform base + lane*16 (linear)
  __builtin_amdgcn_global_load_lds((const GAS void*)g, (LAS void*)l, 16, 0, 0);
}

// (GATE used only by attn)
#define GATE(N)                                            \
  __builtin_amdgcn_sched_barrier(0);                       \
  asm volatile("s_waitcnt vmcnt(" #N ")" ::: "memory");    \
  __builtin_amdgcn_s_barrier();                            \
  __builtin_amdgcn_sched_barrier(0);

// ---------------- prep: 4x W transpose + X convert, one launch -------------
__global__ __launch_bounds__(256) void prep_kernel(const float* __restrict__ X,
                                                   const float* __restrict__ W0,
                                                   const float* __restrict__ W1,
                                                   const float* __restrict__ W2,
                                                   const float* __restrict__ W3,
                                                   short* __restrict__ Xbf,
                                                   short* __restrict__ Wt) {
  const int z = blockIdx.z;
  const int t = threadIdx.x;
  if (z == 4) {
    const int bid = blockIdx.x * 16 + blockIdx.y;
    const float4* src = (const float4*)X;
    short4* dst = (short4*)Xbf;
#pragma unroll
    for (int i = 0; i < 32; ++i) {
      const int idx = bid * 8192 + i * 256 + t;
      float4 v = src[idx];
      short4 o;
      o.x = f2bf(v.x); o.y = f2bf(v.y); o.z = f2bf(v.z); o.w = f2bf(v.w);
      dst[idx] = o;
    }
    return;
  }
  __shared__ short tile[64][65];
  const float* W = (z == 0) ? W0 : (z == 1) ? W1 : (z == 2) ? W2 : W3;
  short* dst = Wt + ((size_t)z << 20);
  const int k0 = blockIdx.x * 64, n0 = blockIdx.y * 64;
#pragma unroll
  for (int i = 0; i < 16; ++i) {
    int r = (t >> 6) + i * 4, c = t & 63;
    tile[r][c] = f2bf(W[(size_t)(k0 + r) * 1024 + n0 + c]);
  }
  __syncthreads();
#pragma unroll
  for (int i = 0; i < 16; ++i) {
    int r = (t >> 6) + i * 4, c = t & 63;
    dst[(size_t)(n0 + r) * 1024 + k0 + c] = tile[c][r];
  }
}

// ---------------- m97-structure bf16 GEMM, 128x128, BK=64 ----------------
// C[M,N] = A[M,1024] @ Bt[N,1024]^T + bias.  BM=BN=128, BK=64.
// 256 thr = 4 waves (2M x 2N), wave tile 64x64 (4x4 16x16 frags, 2 kk).
// LDS: 2 buffers x 32KB = 64KB -> 2 blocks/CU.  Plain __syncthreads per
// K-step (16 steps); stage(kt+1) before compute(kt); compiler scheduling.
// Swizzle (64-col rows, 8 chunks/row): phys = chunk ^ (row&7).
template <int MODE>
__global__ __launch_bounds__(256, 2) void gemmS(const short* __restrict__ A,
                                                const short* __restrict__ Bt,
                                                const float* __restrict__ b0,
                                                const float* __restrict__ b1,
                                                const float* __restrict__ b2,
                                                void* __restrict__ O0,
                                                void* __restrict__ O1,
                                                void* __restrict__ O2) {
  __shared__ short lds[2][16384];  // [buf][ A:0..8191 | B:8192..16383 ]
  const int xcd = (int)blockIdx.x & 7;
  const int t = (int)blockIdx.x >> 3;
  const int m0 = (xcd * 8 + (t & 7)) * 128;  // 8 m-tiles chunked per XCD
  const int n0 = (t >> 3) * 128;             // N advances within chunk
  const int tid = threadIdx.x;
  const int lane = tid & 63, w = tid >> 6;
  const int l15 = lane & 15, lg = lane >> 4;
  const int wm = w >> 1, wn = w & 1;

  const short* ag[4];
  const short* bg[4];
#pragma unroll
  for (int i = 0; i < 4; ++i) {
    const int P = i * 256 + w * 64 + lane;   // physical 16B chunk 0..1023
    const int row = P >> 3, cl = (P & 7) ^ (row & 7);
    ag[i] = A + (size_t)(m0 + row) * 1024 + cl * 8;
    bg[i] = Bt + (size_t)(n0 + row) * 1024 + cl * 8;
  }

  int aof[4], bof[4];
#pragma unroll
  for (int f = 0; f < 4; ++f) {
    const int ra = wm * 64 + f * 16 + l15;
    aof[f] = ra * 64 + ((lg ^ (ra & 7)) * 8);
    const int rb = wn * 64 + f * 16 + l15;
    bof[f] = 8192 + rb * 64 + ((lg ^ (rb & 7)) * 8);
  }

  f32x4 acc[4][4];
#pragma unroll
  for (int i = 0; i < 4; ++i)
#pragma unroll
    for (int j = 0; j < 4; ++j) acc[i][j] = (f32x4){0.f, 0.f, 0.f, 0.f};

  auto stage = [&](int bi, int kt) {
#pragma unroll
    for (int i = 0; i < 4; ++i) {
      gload_lds16(ag[i] + kt * 64, &lds[bi][(i * 256 + w * 64) * 8]);
      gload_lds16(bg[i] + kt * 64, &lds[bi][8192 + (i * 256 + w * 64) * 8]);
    }
  };

  auto compute = [&](int bi) {
    const short* sl = &lds[bi][0];
#pragma unroll
    for (int kk = 0; kk < 2; ++kk) {
      bf16x8 a[4], b[4];
#pragma unroll
      for (int mf = 0; mf < 4; ++mf) a[mf] = *(const bf16x8*)&sl[aof[mf] ^ (kk * 32)];
#pragma unroll
      for (int nf = 0; nf < 4; ++nf) b[nf] = *(const bf16x8*)&sl[bof[nf] ^ (kk * 32)];
#pragma unroll
      for (int mf = 0; mf < 4; ++mf)
#pragma unroll
        for (int nf = 0; nf < 4; ++nf)
          acc[mf][nf] =
              __builtin_amdgcn_mfma_f32_16x16x32_bf16(a[mf], b[nf], acc[mf][nf], 0, 0, 0);
    }
  };

  stage(0, 0);
  __syncthreads();
  int cur = 0;
  for (int kt = 0; kt < 16; ++kt) {
    if (kt + 1 < 16) stage(cur ^ 1, kt + 1);
    compute(cur);
    __syncthreads();
    cur ^= 1;
  }

  if (MODE == 1) {
    float* dst = (float*)O0;
#pragma unroll
    for (int mf = 0; mf < 4; ++mf)
#pragma unroll
      for (int nf = 0; nf < 4; ++nf) {
        const int col = n0 + wn * 64 + nf * 16 + l15;
        const float bv = b0[col];
#pragma unroll
        for (int rr = 0; rr < 4; ++rr) {
          const int row = m0 + wm * 64 + mf * 16 + lg * 4 + rr;
          dst[(size_t)row * 1024 + col] = acc[mf][nf][rr] + bv;
        }
      }
  } else {
    const int mat = n0 >> 10;  // 0=Q 1=K 2=V
    const int nc0 = n0 & 1023;
    const float* bias = (mat == 0) ? b0 : (mat == 1) ? b1 : b2;
    if (mat < 2) {
      short* dst = (short*)(mat == 0 ? O0 : O1);
#pragma unroll
      for (int mf = 0; mf < 4; ++mf)
#pragma unroll
        for (int nf = 0; nf < 4; ++nf) {
          const int col = nc0 + wn * 64 + nf * 16 + l15;
          const float bv = bias[col];
          const int h = col >> 6, hd = col & 63;
#pragma unroll
          for (int rr = 0; rr < 4; ++rr) {
            const int row = m0 + wm * 64 + mf * 16 + lg * 4 + rr;
            const int b = row >> 11, s = row & 2047;
            dst[((size_t)(b * 16 + h) * 2048 + s) * 64 + hd] = f2bf(acc[mf][nf][rr] + bv);
          }
        }
    } else {
      // V: transposed AND k-permuted into Vt [B*16+h][64][2048]:
      // within each 32-k group, stored pos = lg*8 + hi*4 + e for k = hi*16+lg*4+e
      short* dst = (short*)O2;
#pragma unroll
      for (int mf = 0; mf < 4; ++mf) {
        const int rowb = m0 + wm * 64 + mf * 16 + lg * 4;
        const int b = rowb >> 11, s = rowb & 2047;
        const int s2 = (s & ~31) | (((s >> 2) & 3) << 3) | (((s >> 4) & 1) << 2);
#pragma unroll
        for (int nf = 0; nf < 4; ++nf) {
          const int col = nc0 + wn * 64 + nf * 16 + l15;
          const float bv = bias[col];
          const int h = col >> 6, hd = col & 63;
          short4 sv;
          sv.x = f2bf(acc[mf][nf][0] + bv);
          sv.y = f2bf(acc[mf][nf][1] + bv);
          sv.z = f2bf(acc[mf][nf][2] + bv);
          sv.w = f2bf(acc[mf][nf][3] + bv);
          *(short4*)&dst[((size_t)(b * 16 + h) * 64 + hd) * 2048 + s2] = sv;
        }
      }
    }
  }
}

// ---------------- flash causal attention, 512 thr, QBLK=256 ----------------
// Q,K: [64bh][2048][64] bf16; Vt: [64bh][64][2048] bf16 (k-permuted);
// out: [B,S,1024] bf16.  8 waves x 32 q-rows; each staged 64-row K/V tile
// feeds 256 q-rows.  Unnormalized p = exp2(s); MFMA ones-column row sums.
// 3-buf ring: 2 loads/wave/tile -> steady-state gate GATE(2).
// Grid 512 (2 blocks/CU): XCD-local bh, heavy jq first (LPT).
__global__ __launch_bounds__(512) void attn_kernel(const short* __restrict__ Q,
                                                   const short* __restrict__ K,
                                                   const short* __restrict__ Vt,
                                                   short* __restrict__ Oout) {
  __shared__ short Ks[3][4096];
  __shared__ short Vs[3][4096];
  const int g = (int)blockIdx.x;
  const int bh = (((g >> 3) & 7) << 3) | (g & 7);
  const int jq = 7 - (g >> 6);
  const int q0 = jq * 256;
  const int tid = threadIdx.x;
  const int lane = tid & 63, w = tid >> 6;  // w in 0..7
  const int l15 = lane & 15, lg = lane >> 4;
  const short* Qb = Q + (size_t)bh * 2048 * 64;
  const short* Kb = K + (size_t)bh * 2048 * 64;
  const short* Vb = Vt + (size_t)bh * 64 * 2048;
  const int b = bh >> 4, h = bh & 15;
  const float SC = 0.18033688011112042f;  // 0.125 * log2(e)
  const int qg0 = q0 + w * 32;

  bf16x8 qf[2][2];
#pragma unroll
  for (int qs = 0; qs < 2; ++qs)
#pragma unroll
    for (int kk = 0; kk < 2; ++kk) {
      bf16x8 rq =
          *(const bf16x8*)&Qb[(size_t)(qg0 + qs * 16 + l15) * 64 + kk * 32 + lg * 8];
      union { uint32_t u[4]; bf16x8 v; } sq;
#pragma unroll
      for (int d = 0; d < 4; ++d)
        sq.u[d] = cvt_pk_bf16(bf2f(rq[2 * d]) * SC, bf2f(rq[2 * d + 1]) * SC);
      qf[qs][kk] = sq.v;
    }

  union { short s[8]; bf16x8 v; } one_u;
#pragma unroll
  for (int i = 0; i < 8; ++i) one_u.s[i] = (short)0x3F80;

  const int Lsw = tid ^ ((tid >> 3) & 7);
  const short* kg = Kb + (size_t)(Lsw >> 3) * 64 + (Lsw & 7) * 8;
  const short* vg = Vb + (size_t)(Lsw >> 3) * 2048 + (Lsw & 7) * 8;

  int kcol[2];
#pragma unroll
  for (int kk = 0; kk < 2; ++kk)
    kcol[kk] = (((kk * 4 + lg) ^ (l15 & 7)) << 3);

  f32x4 o[2][4];
#pragma unroll
  for (int i = 0; i < 2; ++i)
#pragma unroll
    for (int j = 0; j < 4; ++j) o[i][j] = (f32x4){0.f, 0.f, 0.f, 0.f};
  f32x4 psacc[2] = {(f32x4){0.f, 0.f, 0.f, 0.f}, (f32x4){0.f, 0.f, 0.f, 0.f}};

  auto stageKV = [&](int bi, int kt) {
    gload_lds16(kg + (size_t)kt * 4096, &Ks[bi][w * 512]);
    gload_lds16(vg + kt * 64, &Vs[bi][w * 512]);
  };

  const int nkt = 4 * jq + 4;
  stageKV(0, 0);
  stageKV(1, 1);

  int cur = 0;
  for (int kt = 0; kt < nkt; ++kt) {
    if (kt + 1 < nkt) {
      GATE(2)   // tile kt's 2 ops retired; kt+1's stay in flight
    } else {
      GATE(0)
    }
    if (kt + 2 < nkt) {
      int nb = cur + 2; if (nb >= 3) nb -= 3;
      stageKV(nb, kt + 2);  // overwrites buffer read at kt-1 (published by GATE)
    }

    if (kt * 64 <= qg0 + 31) {  // wave-uniform skip of fully-masked tiles
      const short* Kc = &Ks[cur][0];
      const short* Vc = &Vs[cur][0];

      f32x4 sacc[4][2];
#pragma unroll
      for (int t = 0; t < 4; ++t)
#pragma unroll
        for (int qs = 0; qs < 2; ++qs) sacc[t][qs] = (f32x4){0.f, 0.f, 0.f, 0.f};
      __builtin_amdgcn_s_setprio(1);
#pragma unroll
      for (int t = 0; t < 4; ++t) {
        const int krow = (t * 16 + l15) * 64;
#pragma unroll
        for (int kk = 0; kk < 2; ++kk) {
          bf16x8 kf = *(const bf16x8*)&Kc[krow + kcol[kk]];
#pragma unroll
          for (int qs = 0; qs < 2; ++qs)
            sacc[t][qs] = __builtin_amdgcn_mfma_f32_16x16x32_bf16(kf, qf[qs][kk],
                                                                  sacc[t][qs], 0, 0, 0);
        }
      }
      __builtin_amdgcn_s_setprio(0);

      if (kt * 64 + 63 > qg0) {
#pragma unroll
        for (int t = 0; t < 4; ++t)
#pragma unroll
          for (int qs = 0; qs < 2; ++qs)
#pragma unroll
            for (int r = 0; r < 4; ++r) {
              const int kg_ = kt * 64 + t * 16 + lg * 4 + r;
              const int qg = qg0 + qs * 16 + l15;
              if (kg_ > qg) sacc[t][qs][r] = -3e38f;
            }
      }

      bf16x8 pa[2][2];
#pragma unroll
      for (int qs = 0; qs < 2; ++qs) {
#pragma unroll
        for (int t = 0; t < 4; ++t)
#pragma unroll
          for (int r = 0; r < 4; ++r)
            sacc[t][qs][r] = __builtin_amdgcn_exp2f(sacc[t][qs][r]);
#pragma unroll
        for (int kk = 0; kk < 2; ++kk) {
          union { uint32_t u[4]; bf16x8 v; } pw;
          pw.u[0] = cvt_pk_bf16(sacc[2 * kk][qs][0], sacc[2 * kk][qs][1]);
          pw.u[1] = cvt_pk_bf16(sacc[2 * kk][qs][2], sacc[2 * kk][qs][3]);
          pw.u[2] = cvt_pk_bf16(sacc[2 * kk + 1][qs][0], sacc[2 * kk + 1][qs][1]);
          pw.u[3] = cvt_pk_bf16(sacc[2 * kk + 1][qs][2], sacc[2 * kk + 1][qs][3]);
          pa[qs][kk] = pw.v;
        }
      }

      __builtin_amdgcn_s_setprio(1);
#pragma unroll
      for (int ds = 0; ds < 4; ++ds) {
        const int vrow = (ds * 16 + l15) * 64;
#pragma unroll
        for (int kk = 0; kk < 2; ++kk) {
          bf16x8 vf = *(const bf16x8*)&Vc[vrow + kcol[kk]];
#pragma unroll
          for (int qs = 0; qs < 2; ++qs)
            o[qs][ds] = __builtin_amdgcn_mfma_f32_16x16x32_bf16(pa[qs][kk], vf,
                                                                o[qs][ds], 0, 0, 0);
        }
      }
#pragma unroll
      for (int qs = 0; qs < 2; ++qs)
#pragma unroll
        for (int kk = 0; kk < 2; ++kk)
          psacc[qs] = __builtin_amdgcn_mfma_f32_16x16x32_bf16(pa[qs][kk], one_u.v,
                                                              psacc[qs], 0, 0, 0);
      __builtin_amdgcn_s_setprio(0);
    }

    cur = cur + 1 == 3 ? 0 : cur + 1;
  }

#pragma unroll
  for (int qs = 0; qs < 2; ++qs) {
    float inv[4];
#pragma unroll
    for (int r = 0; r < 4; ++r) inv[r] = 1.f / psacc[qs][r];
#pragma unroll
    for (int ds = 0; ds < 4; ++ds)
#pragma unroll
      for (int r = 0; r < 4; ++r) {
        const int qg = qg0 + qs * 16 + lg * 4 + r;
        const int col = h * 64 + ds * 16 + l15;
        Oout[((size_t)(b * 2048 + qg)) * 1024 + col] = f2bf(o[qs][ds][r] * inv[r]);
      }
  }
}

// ---------------------------------------------------------------------------
extern "C" void kernel_launch(void* const* d_in, const int* in_sizes, int n_in,
                              void* d_out, int out_size, void* d_ws, size_t ws_size,
                              hipStream_t stream) {
  const float* hs = (const float*)d_in[0];
  const float* Wq = (const float*)d_in[1];
  const float* bq = (const float*)d_in[2];
  const float* Wk = (const float*)d_in[3];
  const float* bk = (const float*)d_in[4];
  const float* Wv = (const float*)d_in[5];
  const float* bv = (const float*)d_in[6];
  const float* Wo = (const float*)d_in[7];
  const float* bo = (const float*)d_in[8];

  char* ws = (char*)d_ws;
  short* Xbf = (short*)(ws + 0);                  // 16 MB, reused as attn out
  short* Qb  = (short*)(ws + ((size_t)16 << 20)); // 16 MB
  short* Kb  = (short*)(ws + ((size_t)32 << 20)); // 16 MB
  short* Vtb = (short*)(ws + ((size_t)48 << 20)); // 16 MB
  short* Wts = (short*)(ws + ((size_t)64 << 20)); // 8 MB: Wqt|Wkt|Wvt|Wot
  short* Wot = Wts + ((size_t)3 << 20);

  prep_kernel<<<dim3(16, 16, 5), 256, 0, stream>>>(hs, Wq, Wk, Wv, Wo, Xbf, Wts);

  // QKV: M=8192 (64 tiles), N=3072 (24 tiles) -> 1536 blocks (6/CU exact)
  gemmS<0><<<1536, 256, 0, stream>>>(Xbf, Wts, bq, bk, bv, Qb, Kb, Vtb);

  attn_kernel<<<512, 512, 0, stream>>>(Qb, Kb, Vtb, Xbf);

  // out-proj: M=8192 (64), N=1024 (8) -> 512 blocks
  gemmS<1><<<512, 256, 0, stream>>>(Xbf, Wot, bo, nullptr, nullptr,
                                    (float*)d_out, nullptr, nullptr);
}

// Round 20
// 135.012 us; speedup vs baseline: 1.0340x; 1.0032x over previous
//
#include <hip/hip_runtime.h>
#include <stdint.h>

// ---------------------------------------------------------------------------
// GPT-2 attention block on gfx950.  B=4, S=2048, D=1024, H=16, HD=64.
//   1. prep:      z<4: W_z fp32 [K][N] -> bf16 [N][K];  z=4: X fp32 -> bf16
//   2. gemmS<0>:  QKV = X@[Wq|Wk|Wv]+b  (m97 structure, 128x128, BK=64)
//   3. attn:      flash causal attention, 512 thr = 8 waves x 32 q-rows,
//                 QBLK=256 shared staging, fixed-shift softmax,
//                 4-buf LDS ring staged 3 tiles ahead (GATE 4/2/0).
//   4. gemmS<1>:  out = attn@Wo + bo, fp32
// ---------------------------------------------------------------------------

#define GAS __attribute__((address_space(1)))
#define LAS __attribute__((address_space(3)))

typedef __attribute__((ext_vector_type(4))) float f32x4;
typedef __attribute__((ext_vector_type(8))) short bf16x8;

__device__ __forceinline__ short f2bf(float f) {
  union { float f; uint32_t u; } v; v.f = f;
  uint32_t r = v.u + 0x7fffu + ((v.u >> 16) & 1u);  // RNE
  return (short)(r >> 16);
}

__device__ __forceinline__ float bf2f(short s) {
  union { uint32_t u; float f; } v;
  v.u = ((uint32_t)(uint16_t)s) << 16;
  return v.f;
}

__device__ __forceinline__ uint32_t cvt_pk_bf16(float lo, float hi) {
  uint32_t r;
  asm("v_cvt_pk_bf16_f32 %0, %1, %2" : "=v"(r) : "v"(lo), "v"(hi));
  return r;
}

__device__ __forceinline__ void gload_lds16(const void* g, void* l) {
  // 16B per lane; LDS dest = wave-uniform base + lane*16 (linear)
  __builtin_amdgcn_global_load_lds((const GAS void*)g, (LAS void*)l, 16, 0, 0);
}

// (GATE used only by attn)
#define GATE(N)                                            \
  __builtin_amdgcn_sched_barrier(0);                       \
  asm volatile("s_waitcnt vmcnt(" #N ")" ::: "memory");    \
  __builtin_amdgcn_s_barrier();                            \
  __builtin_amdgcn_sched_barrier(0);

// ---------------- prep: 4x W transpose + X convert, one launch -------------
__global__ __launch_bounds__(256) void prep_kernel(const float* __restrict__ X,
                                                   const float* __restrict__ W0,
                                                   const float* __restrict__ W1,
                                                   const float* __restrict__ W2,
                                                   const float* __restrict__ W3,
                                                   short* __restrict__ Xbf,
                                                   short* __restrict__ Wt) {
  const int z = blockIdx.z;
  const int t = threadIdx.x;
  if (z == 4) {
    const int bid = blockIdx.x * 16 + blockIdx.y;
    const float4* src = (const float4*)X;
    short4* dst = (short4*)Xbf;
#pragma unroll
    for (int i = 0; i < 32; ++i) {
      const int idx = bid * 8192 + i * 256 + t;
      float4 v = src[idx];
      short4 o;
      o.x = f2bf(v.x); o.y = f2bf(v.y); o.z = f2bf(v.z); o.w = f2bf(v.w);
      dst[idx] = o;
    }
    return;
  }
  __shared__ short tile[64][65];
  const float* W = (z == 0) ? W0 : (z == 1) ? W1 : (z == 2) ? W2 : W3;
  short* dst = Wt + ((size_t)z << 20);
  const int k0 = blockIdx.x * 64, n0 = blockIdx.y * 64;
#pragma unroll
  for (int i = 0; i < 16; ++i) {
    int r = (t >> 6) + i * 4, c = t & 63;
    tile[r][c] = f2bf(W[(size_t)(k0 + r) * 1024 + n0 + c]);
  }
  __syncthreads();
#pragma unroll
  for (int i = 0; i < 16; ++i) {
    int r = (t >> 6) + i * 4, c = t & 63;
    dst[(size_t)(n0 + r) * 1024 + k0 + c] = tile[c][r];
  }
}

// ---------------- m97-structure bf16 GEMM, 128x128, BK=64 ----------------
template <int MODE>
__global__ __launch_bounds__(256, 2) void gemmS(const short* __restrict__ A,
                                                const short* __restrict__ Bt,
                                                const float* __restrict__ b0,
                                                const float* __restrict__ b1,
                                                const float* __restrict__ b2,
                                                void* __restrict__ O0,
                                                void* __restrict__ O1,
                                                void* __restrict__ O2) {
  __shared__ short lds[2][16384];  // [buf][ A:0..8191 | B:8192..16383 ]
  const int xcd = (int)blockIdx.x & 7;
  const int t = (int)blockIdx.x >> 3;
  const int m0 = (xcd * 8 + (t & 7)) * 128;  // 8 m-tiles chunked per XCD
  const int n0 = (t >> 3) * 128;             // N advances within chunk
  const int tid = threadIdx.x;
  const int lane = tid & 63, w = tid >> 6;
  const int l15 = lane & 15, lg = lane >> 4;
  const int wm = w >> 1, wn = w & 1;

  const short* ag[4];
  const short* bg[4];
#pragma unroll
  for (int i = 0; i < 4; ++i) {
    const int P = i * 256 + w * 64 + lane;   // physical 16B chunk 0..1023
    const int row = P >> 3, cl = (P & 7) ^ (row & 7);
    ag[i] = A + (size_t)(m0 + row) * 1024 + cl * 8;
    bg[i] = Bt + (size_t)(n0 + row) * 1024 + cl * 8;
  }

  int aof[4], bof[4];
#pragma unroll
  for (int f = 0; f < 4; ++f) {
    const int ra = wm * 64 + f * 16 + l15;
    aof[f] = ra * 64 + ((lg ^ (ra & 7)) * 8);
    const int rb = wn * 64 + f * 16 + l15;
    bof[f] = 8192 + rb * 64 + ((lg ^ (rb & 7)) * 8);
  }

  f32x4 acc[4][4];
#pragma unroll
  for (int i = 0; i < 4; ++i)
#pragma unroll
    for (int j = 0; j < 4; ++j) acc[i][j] = (f32x4){0.f, 0.f, 0.f, 0.f};

  auto stage = [&](int bi, int kt) {
#pragma unroll
    for (int i = 0; i < 4; ++i) {
      gload_lds16(ag[i] + kt * 64, &lds[bi][(i * 256 + w * 64) * 8]);
      gload_lds16(bg[i] + kt * 64, &lds[bi][8192 + (i * 256 + w * 64) * 8]);
    }
  };

  auto compute = [&](int bi) {
    const short* sl = &lds[bi][0];
#pragma unroll
    for (int kk = 0; kk < 2; ++kk) {
      bf16x8 a[4], b[4];
#pragma unroll
      for (int mf = 0; mf < 4; ++mf) a[mf] = *(const bf16x8*)&sl[aof[mf] ^ (kk * 32)];
#pragma unroll
      for (int nf = 0; nf < 4; ++nf) b[nf] = *(const bf16x8*)&sl[bof[nf] ^ (kk * 32)];
#pragma unroll
      for (int mf = 0; mf < 4; ++mf)
#pragma unroll
        for (int nf = 0; nf < 4; ++nf)
          acc[mf][nf] =
              __builtin_amdgcn_mfma_f32_16x16x32_bf16(a[mf], b[nf], acc[mf][nf], 0, 0, 0);
    }
  };

  stage(0, 0);
  __syncthreads();
  int cur = 0;
  for (int kt = 0; kt < 16; ++kt) {
    if (kt + 1 < 16) stage(cur ^ 1, kt + 1);
    compute(cur);
    __syncthreads();
    cur ^= 1;
  }

  if (MODE == 1) {
    float* dst = (float*)O0;
#pragma unroll
    for (int mf = 0; mf < 4; ++mf)
#pragma unroll
      for (int nf = 0; nf < 4; ++nf) {
        const int col = n0 + wn * 64 + nf * 16 + l15;
        const float bv = b0[col];
#pragma unroll
        for (int rr = 0; rr < 4; ++rr) {
          const int row = m0 + wm * 64 + mf * 16 + lg * 4 + rr;
          dst[(size_t)row * 1024 + col] = acc[mf][nf][rr] + bv;
        }
      }
  } else {
    const int mat = n0 >> 10;  // 0=Q 1=K 2=V
    const int nc0 = n0 & 1023;
    const float* bias = (mat == 0) ? b0 : (mat == 1) ? b1 : b2;
    if (mat < 2) {
      short* dst = (short*)(mat == 0 ? O0 : O1);
#pragma unroll
      for (int mf = 0; mf < 4; ++mf)
#pragma unroll
        for (int nf = 0; nf < 4; ++nf) {
          const int col = nc0 + wn * 64 + nf * 16 + l15;
          const float bv = bias[col];
          const int h = col >> 6, hd = col & 63;
#pragma unroll
          for (int rr = 0; rr < 4; ++rr) {
            const int row = m0 + wm * 64 + mf * 16 + lg * 4 + rr;
            const int b = row >> 11, s = row & 2047;
            dst[((size_t)(b * 16 + h) * 2048 + s) * 64 + hd] = f2bf(acc[mf][nf][rr] + bv);
          }
        }
    } else {
      // V: transposed AND k-permuted into Vt [B*16+h][64][2048]:
      // within each 32-k group, stored pos = lg*8 + hi*4 + e for k = hi*16+lg*4+e
      short* dst = (short*)O2;
#pragma unroll
      for (int mf = 0; mf < 4; ++mf) {
        const int rowb = m0 + wm * 64 + mf * 16 + lg * 4;
        const int b = rowb >> 11, s = rowb & 2047;
        const int s2 = (s & ~31) | (((s >> 2) & 3) << 3) | (((s >> 4) & 1) << 2);
#pragma unroll
        for (int nf = 0; nf < 4; ++nf) {
          const int col = nc0 + wn * 64 + nf * 16 + l15;
          const float bv = bias[col];
          const int h = col >> 6, hd = col & 63;
          short4 sv;
          sv.x = f2bf(acc[mf][nf][0] + bv);
          sv.y = f2bf(acc[mf][nf][1] + bv);
          sv.z = f2bf(acc[mf][nf][2] + bv);
          sv.w = f2bf(acc[mf][nf][3] + bv);
          *(short4*)&dst[((size_t)(b * 16 + h) * 64 + hd) * 2048 + s2] = sv;
        }
      }
    }
  }
}

// ---------------- flash causal attention, 512 thr, QBLK=256 ----------------
// Q,K: [64bh][2048][64] bf16; Vt: [64bh][64][2048] bf16 (k-permuted);
// out: [B,S,1024] bf16.  8 waves x 32 q-rows; each staged 64-row K/V tile
// feeds 256 q-rows.  Unnormalized p = exp2(s); MFMA ones-column row sums.
// 4-buffer LDS ring staged 3 tiles ahead (2 loads/wave/tile): steady-state
// gate vmcnt(4) = tile kt retired, kt+1/kt+2 in flight; tail 2 -> 0.
// Grid 512 (2 blocks/CU): XCD-local bh, heavy jq first (LPT).
__global__ __launch_bounds__(512) void attn_kernel(const short* __restrict__ Q,
                                                   const short* __restrict__ K,
                                                   const short* __restrict__ Vt,
                                                   short* __restrict__ Oout) {
  __shared__ short Ks[4][4096];
  __shared__ short Vs[4][4096];
  const int g = (int)blockIdx.x;
  const int bh = (((g >> 3) & 7) << 3) | (g & 7);
  const int jq = 7 - (g >> 6);
  const int q0 = jq * 256;
  const int tid = threadIdx.x;
  const int lane = tid & 63, w = tid >> 6;  // w in 0..7
  const int l15 = lane & 15, lg = lane >> 4;
  const short* Qb = Q + (size_t)bh * 2048 * 64;
  const short* Kb = K + (size_t)bh * 2048 * 64;
  const short* Vb = Vt + (size_t)bh * 64 * 2048;
  const int b = bh >> 4, h = bh & 15;
  const float SC = 0.18033688011112042f;  // 0.125 * log2(e)
  const int qg0 = q0 + w * 32;

  bf16x8 qf[2][2];
#pragma unroll
  for (int qs = 0; qs < 2; ++qs)
#pragma unroll
    for (int kk = 0; kk < 2; ++kk) {
      bf16x8 rq =
          *(const bf16x8*)&Qb[(size_t)(qg0 + qs * 16 + l15) * 64 + kk * 32 + lg * 8];
      union { uint32_t u[4]; bf16x8 v; } sq;
#pragma unroll
      for (int d = 0; d < 4; ++d)
        sq.u[d] = cvt_pk_bf16(bf2f(rq[2 * d]) * SC, bf2f(rq[2 * d + 1]) * SC);
      qf[qs][kk] = sq.v;
    }

  union { short s[8]; bf16x8 v; } one_u;
#pragma unroll
  for (int i = 0; i < 8; ++i) one_u.s[i] = (short)0x3F80;

  const int Lsw = tid ^ ((tid >> 3) & 7);
  const short* kg = Kb + (size_t)(Lsw >> 3) * 64 + (Lsw & 7) * 8;
  const short* vg = Vb + (size_t)(Lsw >> 3) * 2048 + (Lsw & 7) * 8;

  int kcol[2];
#pragma unroll
  for (int kk = 0; kk < 2; ++kk)
    kcol[kk] = (((kk * 4 + lg) ^ (l15 & 7)) << 3);

  f32x4 o[2][4];
#pragma unroll
  for (int i = 0; i < 2; ++i)
#pragma unroll
    for (int j = 0; j < 4; ++j) o[i][j] = (f32x4){0.f, 0.f, 0.f, 0.f};
  f32x4 psacc[2] = {(f32x4){0.f, 0.f, 0.f, 0.f}, (f32x4){0.f, 0.f, 0.f, 0.f}};

  auto stageKV = [&](int bi, int kt) {
    gload_lds16(kg + (size_t)kt * 4096, &Ks[bi][w * 512]);
    gload_lds16(vg + kt * 64, &Vs[bi][w * 512]);
  };

  const int nkt = 4 * jq + 4;  // >= 4
  // prologue: 3 tiles in flight (2 loads/wave each)
  stageKV(0, 0);
  stageKV(1, 1);
  stageKV(2, 2);

  int cur = 0;
  for (int kt = 0; kt < nkt; ++kt) {
    const int rem = nkt - 1 - kt;  // tiles after this one
    if (rem >= 2) {
      GATE(4)   // tile kt retired; kt+1, kt+2 (4 ops) stay in flight
    } else if (rem == 1) {
      GATE(2)
    } else {
      GATE(0)
    }
    if (kt + 3 < nkt) {
      stageKV((cur + 3) & 3, kt + 3);  // buf (kt-1)&3: reads done, published
    }

    if (kt * 64 <= qg0 + 31) {  // wave-uniform skip of fully-masked tiles
      const short* Kc = &Ks[cur][0];
      const short* Vc = &Vs[cur][0];

      f32x4 sacc[4][2];
#pragma unroll
      for (int t = 0; t < 4; ++t)
#pragma unroll
        for (int qs = 0; qs < 2; ++qs) sacc[t][qs] = (f32x4){0.f, 0.f, 0.f, 0.f};
      __builtin_amdgcn_s_setprio(1);
#pragma unroll
      for (int t = 0; t < 4; ++t) {
        const int krow = (t * 16 + l15) * 64;
#pragma unroll
        for (int kk = 0; kk < 2; ++kk) {
          bf16x8 kf = *(const bf16x8*)&Kc[krow + kcol[kk]];
#pragma unroll
          for (int qs = 0; qs < 2; ++qs)
            sacc[t][qs] = __builtin_amdgcn_mfma_f32_16x16x32_bf16(kf, qf[qs][kk],
                                                                  sacc[t][qs], 0, 0, 0);
        }
      }
      __builtin_amdgcn_s_setprio(0);

      if (kt * 64 + 63 > qg0) {
#pragma unroll
        for (int t = 0; t < 4; ++t)
#pragma unroll
          for (int qs = 0; qs < 2; ++qs)
#pragma unroll
            for (int r = 0; r < 4; ++r) {
              const int kg_ = kt * 64 + t * 16 + lg * 4 + r;
              const int qg = qg0 + qs * 16 + l15;
              if (kg_ > qg) sacc[t][qs][r] = -3e38f;
            }
      }

      bf16x8 pa[2][2];
#pragma unroll
      for (int qs = 0; qs < 2; ++qs) {
#pragma unroll
        for (int t = 0; t < 4; ++t)
#pragma unroll
          for (int r = 0; r < 4; ++r)
            sacc[t][qs][r] = __builtin_amdgcn_exp2f(sacc[t][qs][r]);
#pragma unroll
        for (int kk = 0; kk < 2; ++kk) {
          union { uint32_t u[4]; bf16x8 v; } pw;
          pw.u[0] = cvt_pk_bf16(sacc[2 * kk][qs][0], sacc[2 * kk][qs][1]);
          pw.u[1] = cvt_pk_bf16(sacc[2 * kk][qs][2], sacc[2 * kk][qs][3]);
          pw.u[2] = cvt_pk_bf16(sacc[2 * kk + 1][qs][0], sacc[2 * kk + 1][qs][1]);
          pw.u[3] = cvt_pk_bf16(sacc[2 * kk + 1][qs][2], sacc[2 * kk + 1][qs][3]);
          pa[qs][kk] = pw.v;
        }
      }

      __builtin_amdgcn_s_setprio(1);
#pragma unroll
      for (int ds = 0; ds < 4; ++ds) {
        const int vrow = (ds * 16 + l15) * 64;
#pragma unroll
        for (int kk = 0; kk < 2; ++kk) {
          bf16x8 vf = *(const bf16x8*)&Vc[vrow + kcol[kk]];
#pragma unroll
          for (int qs = 0; qs < 2; ++qs)
            o[qs][ds] = __builtin_amdgcn_mfma_f32_16x16x32_bf16(pa[qs][kk], vf,
                                                                o[qs][ds], 0, 0, 0);
        }
      }
#pragma unroll
      for (int qs = 0; qs < 2; ++qs)
#pragma unroll
        for (int kk = 0; kk < 2; ++kk)
          psacc[qs] = __builtin_amdgcn_mfma_f32_16x16x32_bf16(pa[qs][kk], one_u.v,
                                                              psacc[qs], 0, 0, 0);
      __builtin_amdgcn_s_setprio(0);
    }

    cur = (cur + 1) & 3;
  }

#pragma unroll
  for (int qs = 0; qs < 2; ++qs) {
    float inv[4];
#pragma unroll
    for (int r = 0; r < 4; ++r) inv[r] = 1.f / psacc[qs][r];
#pragma unroll
    for (int ds = 0; ds < 4; ++ds)
#pragma unroll
      for (int r = 0; r < 4; ++r) {
        const int qg = qg0 + qs * 16 + lg * 4 + r;
        const int col = h * 64 + ds * 16 + l15;
        Oout[((size_t)(b * 2048 + qg)) * 1024 + col] = f2bf(o[qs][ds][r] * inv[r]);
      }
  }
}

// ---------------------------------------------------------------------------
extern "C" void kernel_launch(void* const* d_in, const int* in_sizes, int n_in,
                              void* d_out, int out_size, void* d_ws, size_t ws_size,
                              hipStream_t stream) {
  const float* hs = (const float*)d_in[0];
  const float* Wq = (const float*)d_in[1];
  const float* bq = (const float*)d_in[2];
  const float* Wk = (const float*)d_in[3];
  const float* bk = (const float*)d_in[4];
  const float* Wv = (const float*)d_in[5];
  const float* bv = (const float*)d_in[6];
  const float* Wo = (const float*)d_in[7];
  const float* bo = (const float*)d_in[8];

  char* ws = (char*)d_ws;
  short* Xbf = (short*)(ws + 0);                  // 16 MB, reused as attn out
  short* Qb  = (short*)(ws + ((size_t)16 << 20)); // 16 MB
  short* Kb  = (short*)(ws + ((size_t)32 << 20)); // 16 MB
  short* Vtb = (short*)(ws + ((size_t)48 << 20)); // 16 MB
  short* Wts = (short*)(ws + ((size_t)64 << 20)); // 8 MB: Wqt|Wkt|Wvt|Wot
  short* Wot = Wts + ((size_t)3 << 20);

  prep_kernel<<<dim3(16, 16, 5), 256, 0, stream>>>(hs, Wq, Wk, Wv, Wo, Xbf, Wts);

  // QKV: M=8192 (64 tiles), N=3072 (24 tiles) -> 1536 blocks (6/CU exact)
  gemmS<0><<<1536, 256, 0, stream>>>(Xbf, Wts, bq, bk, bv, Qb, Kb, Vtb);

  attn_kernel<<<512, 512, 0, stream>>>(Qb, Kb, Vtb, Xbf);

  // out-proj: M=8192 (64), N=1024 (8) -> 512 blocks
  gemmS<1><<<512, 256, 0, stream>>>(Xbf, Wot, bo, nullptr, nullptr,
                                    (float*)d_out, nullptr, nullptr);
}